// Round 5
// baseline (533.386 us; speedup 1.0000x reference)
//
#include <hip/hip_runtime.h>
#include <hip/hip_bf16.h>

#define VN    64
#define KPAD  264   // sh_hb bf16 stride: rows 16B-aligned (528B)

typedef __bf16 bf16x8 __attribute__((ext_vector_type(8)));
typedef float  f32x4  __attribute__((ext_vector_type(4)));

// packed-weight bf16 element offsets in d_ws
#define OFF_W0   0
#define OFF_SK0  40960
#define OFF_W1   81920
#define OFF_SK1  147456
#define OFF_W2   212992
#define OFF_SK2  278528
#define OFF_W3   344064
#define OFF_H1W  409600
#define OFF_END  475136            // end of packed weights (bf16 elems)

__global__ void conv_pack(const float* __restrict__ src, __bf16* __restrict__ dst,
                          int fin, int kp)
{
  int idx = blockIdx.x * 256 + threadIdx.x;
  if (idx >= kp * 256) return;
  int r = idx & 7, n = (idx >> 3) & 255, c = idx >> 11;
  int k = c * 8 + r;
  float v = (k < fin) ? src[k * 256 + n] : 0.0f;
  dst[idx] = (__bf16)v;
}

__global__ void transpose_h2w(const float* __restrict__ h2W, float* __restrict__ h2wt)
{
  int idx = threadIdx.x;          // 512 threads
  int c = idx >> 8, k = idx & 255;
  h2wt[idx] = h2W[k * 2 + c];
}

__global__ void temb_kernel(const int* __restrict__ t, const float* __restrict__ tW,
                            const float* __restrict__ tb, float* __restrict__ d_temb)
{
  __shared__ float se[128];
  int b = blockIdx.x, tid = threadIdx.x;
  int fi = tid & 63;
  float fr = expf(-logf(10000.0f) * (float)fi / 63.0f);
  float te = (float)t[b] * fr;
  se[tid] = (tid < 64) ? sinf(te) : cosf(te);
  __syncthreads();
  float a = tb[tid];
  for (int k = 0; k < 128; k++)
    a = fmaf(se[k], tW[k * 128 + tid], a);
  d_temb[b * 128 + tid] = a / (1.0f + expf(-a));
}

// single-B matmul: acc += A(64 x 32*KS from LDS) @ B(packed global)
template<int KS>
__device__ __forceinline__ void mfma_mm(const __bf16* __restrict__ Bp,
                                        f32x4 acc[4][4],
                                        const __bf16* __restrict__ shA,
                                        int l, int q, int colbase8)
{
#pragma unroll
  for (int s = 0; s < KS; s++) {
    bf16x8 af[4], bfr[4];
#pragma unroll
    for (int rt = 0; rt < 4; rt++)
      af[rt] = *(const bf16x8*)(shA + (rt * 16 + l) * KPAD + s * 32 + q * 8);
#pragma unroll
    for (int ct = 0; ct < 4; ct++)
      bfr[ct] = *(const bf16x8*)(Bp + (s * 4 + q) * 2048 + colbase8 + ct * 128);
#pragma unroll
    for (int rt = 0; rt < 4; rt++)
#pragma unroll
      for (int ct = 0; ct < 4; ct++)
        acc[rt][ct] = __builtin_amdgcn_mfma_f32_16x16x32_bf16(af[rt], bfr[ct], acc[rt][ct], 0, 0, 0);
  }
}

// dual-B matmul: shared A fragments, accW += A@Bw, accK += A@Bk
template<int KS>
__device__ __forceinline__ void mfma_dual(const __bf16* __restrict__ Bw,
                                          const __bf16* __restrict__ Bk,
                                          f32x4 accW[4][4], f32x4 accK[4][4],
                                          const __bf16* __restrict__ shA,
                                          int l, int q, int colbase8)
{
#pragma unroll
  for (int s = 0; s < KS; s++) {
    bf16x8 af[4], bw[4], bk[4];
#pragma unroll
    for (int rt = 0; rt < 4; rt++)
      af[rt] = *(const bf16x8*)(shA + (rt * 16 + l) * KPAD + s * 32 + q * 8);
#pragma unroll
    for (int ct = 0; ct < 4; ct++) {
      bw[ct] = *(const bf16x8*)(Bw + (s * 4 + q) * 2048 + colbase8 + ct * 128);
      bk[ct] = *(const bf16x8*)(Bk + (s * 4 + q) * 2048 + colbase8 + ct * 128);
    }
#pragma unroll
    for (int rt = 0; rt < 4; rt++)
#pragma unroll
      for (int ct = 0; ct < 4; ct++) {
        accW[rt][ct] = __builtin_amdgcn_mfma_f32_16x16x32_bf16(af[rt], bw[ct], accW[rt][ct], 0, 0, 0);
        accK[rt][ct] = __builtin_amdgcn_mfma_f32_16x16x32_bf16(af[rt], bk[ct], accK[rt][ct], 0, 0, 0);
      }
  }
}

__global__ __launch_bounds__(256, 2)
void gat_poly_kernel(const float* __restrict__ x,
                     const float* __restrict__ as0, const float* __restrict__ at0, const float* __restrict__ b0,
                     const float* __restrict__ as1, const float* __restrict__ at1, const float* __restrict__ b1,
                     const float* __restrict__ as2, const float* __restrict__ at2, const float* __restrict__ b2,
                     const float* __restrict__ as3, const float* __restrict__ at3, const float* __restrict__ b3,
                     const float* __restrict__ h1b, const float* __restrict__ h2b,
                     const __bf16* __restrict__ WP,
                     const float* __restrict__ h2wt,
                     const float* __restrict__ d_temb,
                     float* __restrict__ out)
{
  __shared__ __bf16 sh_hb[VN * KPAD];   // activations bf16 (MFMA A source)
  __shared__ float  sh_temb[128];
  __shared__ float  sh_ssp[VN * 4];     // layer-3 per-wave score partials
  __shared__ float  sh_stp[VN * 4];
  __shared__ float  sh_al[VN][3];       // layer-3 alphas

  const int b    = blockIdx.x;
  const int tid  = threadIdx.x;
  const int w    = tid >> 6;
  const int lane = tid & 63;
  const int l    = lane & 15;
  const int q    = lane >> 4;
  const int cb   = w * 64;
  const int colbase8 = (cb + l) * 8;
  const int lup  = (lane + 16) & 63;    // q+1 group (wraps)
  const int ldn  = (lane + 48) & 63;    // q-1 group (wraps)

  float h2r[4][4][4];   // layer-2 output (fp32) for the layer-3 identity residual

  if (tid < 128) sh_temb[tid] = d_temb[b * 128 + tid];
  __syncthreads();

  // ------------- h0 = [coords(2), pos(4), temb(128)], zero pad to 160 --------
  for (int idx = tid; idx < VN * 160; idx += 256) {
    int n = idx / 160, k = idx - n * 160;
    float v = 0.0f;
    if (k < 2) {
      v = x[b * 128 + 2 * n + k];
    } else if (k < 6) {
      float ph  = (float)n * 0.09817477042468103f;  // 2*pi/64
      float arg = (k < 4) ? ph : 2.0f * ph;
      v = ((k & 1) == 0) ? sinf(arg) : cosf(arg);
    } else if (k < 134) {
      v = sh_temb[k - 6];
    }
    sh_hb[n * KPAD + k] = (__bf16)v;
  }
  __syncthreads();

  const int WOFFS[3]  = {OFF_W0, OFF_W1, OFF_W2};
  const int SOFFS[3]  = {OFF_SK0, OFF_SK1, OFF_SK2};
  const float* Asr[3] = {as0, as1, as2};
  const float* Atg[3] = {at0, at1, at2};
  const float* Bs[3]  = {b0, b1, b2};

  // ---------------- GAT layers 0..2 (NH=4, FOUT=64, concat + elu) ------------
  for (int li = 0; li < 3; li++) {
    f32x4 accP[4][4], accS[4][4];
#pragma unroll
    for (int rt = 0; rt < 4; rt++)
#pragma unroll
      for (int ct = 0; ct < 4; ct++) { accP[rt][ct] = (f32x4)0.0f; accS[rt][ct] = (f32x4)0.0f; }

    if (li == 0) mfma_dual<5>(WP + OFF_W0,   WP + OFF_SK0,   accP, accS, sh_hb, l, q, colbase8);
    else         mfma_dual<8>(WP + WOFFS[li], WP + SOFFS[li], accP, accS, sh_hb, l, q, colbase8);

    // -------- scores: wave w == head w; fully in-register ----------
    float ca[4], ta[4];
#pragma unroll
    for (int ct = 0; ct < 4; ct++) {
      ca[ct] = Asr[li][cb + ct * 16 + l];
      ta[ct] = Atg[li][cb + ct * 16 + l];
    }
    float ssA[4][4], stA[4][4];
#pragma unroll
    for (int rt = 0; rt < 4; rt++)
#pragma unroll
      for (int reg = 0; reg < 4; reg++) {
        float ss = accP[rt][0][reg] * ca[0] + accP[rt][1][reg] * ca[1]
                 + accP[rt][2][reg] * ca[2] + accP[rt][3][reg] * ca[3];
        float st = accP[rt][0][reg] * ta[0] + accP[rt][1][reg] * ta[1]
                 + accP[rt][2][reg] * ta[2] + accP[rt][3][reg] * ta[3];
#pragma unroll
        for (int m = 8; m >= 1; m >>= 1) {
          ss += __shfl_xor(ss, m, 64);
          st += __shfl_xor(st, m, 64);
        }
        ssA[rt][reg] = ss;
        stA[rt][reg] = st;
      }

    // -------- softmax over {prv,nxt,self} edges, in-register --------
    float al0[4][4], al1[4][4], al2[4][4];
    {
      float s0s[4], s3s[4];
#pragma unroll
      for (int rt = 0; rt < 4; rt++) {
        s0s[rt] = __shfl(ssA[rt][0], lup, 64);
        s3s[rt] = __shfl(ssA[rt][3], ldn, 64);
      }
#pragma unroll
      for (int rt = 0; rt < 4; rt++)
#pragma unroll
        for (int reg = 0; reg < 4; reg++) {
          float ssp = (reg > 0) ? ssA[rt][reg - 1] : ((q > 0) ? s3s[rt] : s3s[(rt + 3) & 3]);
          float ssx = (reg < 3) ? ssA[rt][reg + 1] : ((q < 3) ? s0s[rt] : s0s[(rt + 1) & 3]);
          float stg = stA[rt][reg];
          float e0 = ssp + stg;          e0 = (e0 < 0.0f) ? 0.2f * e0 : e0;
          float e1 = ssx + stg;          e1 = (e1 < 0.0f) ? 0.2f * e1 : e1;
          float e2 = ssA[rt][reg] + stg; e2 = (e2 < 0.0f) ? 0.2f * e2 : e2;
          float mx = fmaxf(e0, fmaxf(e1, e2));
          float x0 = expf(e0 - mx), x1 = expf(e1 - mx), x2 = expf(e2 - mx);
          float inv = 1.0f / (x0 + x1 + x2 + 1e-16f);
          al0[rt][reg] = x0 * inv;
          al1[rt][reg] = x1 * inv;
          al2[rt][reg] = x2 * inv;
        }
    }

    __syncthreads();   // all waves done reading sh_hb

    // -------- epilogue: skip + alpha-weighted neighbor gather (shuffles) -----
    {
      float b4[4];
#pragma unroll
      for (int ct = 0; ct < 4; ct++) b4[ct] = Bs[li][cb + ct * 16 + l];
#pragma unroll
      for (int ct = 0; ct < 4; ct++) {
        float p0s[4], p3s[4];
#pragma unroll
        for (int rt = 0; rt < 4; rt++) {
          p0s[rt] = __shfl(accP[rt][ct][0], lup, 64);
          p3s[rt] = __shfl(accP[rt][ct][3], ldn, 64);
        }
#pragma unroll
        for (int rt = 0; rt < 4; rt++)
#pragma unroll
          for (int reg = 0; reg < 4; reg++) {
            float pv = (reg > 0) ? accP[rt][ct][reg - 1] : ((q > 0) ? p3s[rt] : p3s[(rt + 3) & 3]);
            float nx = (reg < 3) ? accP[rt][ct][reg + 1] : ((q < 3) ? p0s[rt] : p0s[(rt + 1) & 3]);
            float o = accS[rt][ct][reg]
                    + al0[rt][reg] * pv + al1[rt][reg] * nx
                    + al2[rt][reg] * accP[rt][ct][reg] + b4[ct];
            o = (o > 0.0f) ? o : (expf(o) - 1.0f);   // elu
            if (li == 2) h2r[rt][ct][reg] = o;       // fp32 residual for layer 3
            sh_hb[(rt * 16 + q * 4 + reg) * KPAD + cb + ct * 16 + l] = (__bf16)o;
          }
      }
    }
    __syncthreads();
  }

  // ---------------- GAT layer 3 (NH=1, FOUT=256, identity skip, no act) ------
  {
    f32x4 accP[4][4];
#pragma unroll
    for (int rt = 0; rt < 4; rt++)
#pragma unroll
      for (int ct = 0; ct < 4; ct++) accP[rt][ct] = (f32x4)0.0f;
    mfma_mm<8>(WP + OFF_W3, accP, sh_hb, l, q, colbase8);

    { // per-wave partial scores over this wave's 64 cols
      float ca[4], ta[4];
#pragma unroll
      for (int ct = 0; ct < 4; ct++) {
        ca[ct] = as3[cb + ct * 16 + l];
        ta[ct] = at3[cb + ct * 16 + l];
      }
#pragma unroll
      for (int rt = 0; rt < 4; rt++)
#pragma unroll
        for (int reg = 0; reg < 4; reg++) {
          float ss = accP[rt][0][reg] * ca[0] + accP[rt][1][reg] * ca[1]
                   + accP[rt][2][reg] * ca[2] + accP[rt][3][reg] * ca[3];
          float st = accP[rt][0][reg] * ta[0] + accP[rt][1][reg] * ta[1]
                   + accP[rt][2][reg] * ta[2] + accP[rt][3][reg] * ta[3];
#pragma unroll
          for (int m = 8; m >= 1; m >>= 1) {
            ss += __shfl_xor(ss, m, 64);
            st += __shfl_xor(st, m, 64);
          }
          if (l == 0) {
            int n = rt * 16 + q * 4 + reg;
            sh_ssp[n * 4 + w] = ss;
            sh_stp[n * 4 + w] = st;
          }
        }
    }
    __syncthreads();   // partials visible; sh_hb reads done

    if (tid < 64) {    // single wave: combine partials + softmax, no extra barrier
      int n = tid;
      float ssn = sh_ssp[n * 4] + sh_ssp[n * 4 + 1] + sh_ssp[n * 4 + 2] + sh_ssp[n * 4 + 3];
      float stn = sh_stp[n * 4] + sh_stp[n * 4 + 1] + sh_stp[n * 4 + 2] + sh_stp[n * 4 + 3];
      float ssp = __shfl(ssn, (n + 63) & 63, 64);
      float ssx = __shfl(ssn, (n + 1) & 63, 64);
      float e0 = ssp + stn; e0 = (e0 < 0.0f) ? 0.2f * e0 : e0;
      float e1 = ssx + stn; e1 = (e1 < 0.0f) ? 0.2f * e1 : e1;
      float e2 = ssn + stn; e2 = (e2 < 0.0f) ? 0.2f * e2 : e2;
      float mx = fmaxf(e0, fmaxf(e1, e2));
      float x0 = expf(e0 - mx), x1 = expf(e1 - mx), x2 = expf(e2 - mx);
      float inv = 1.0f / (x0 + x1 + x2 + 1e-16f);
      sh_al[n][0] = x0 * inv;
      sh_al[n][1] = x1 * inv;
      sh_al[n][2] = x2 * inv;
    }
    __syncthreads();

    { // epilogue: alpha gather (shuffles) + fp32 residual + b3
      float b4[4];
#pragma unroll
      for (int ct = 0; ct < 4; ct++) b4[ct] = b3[cb + ct * 16 + l];
      float a0r[4][4], a1r[4][4], a2r[4][4];
#pragma unroll
      for (int rt = 0; rt < 4; rt++)
#pragma unroll
        for (int reg = 0; reg < 4; reg++) {
          int n = rt * 16 + q * 4 + reg;
          a0r[rt][reg] = sh_al[n][0];
          a1r[rt][reg] = sh_al[n][1];
          a2r[rt][reg] = sh_al[n][2];
        }
#pragma unroll
      for (int ct = 0; ct < 4; ct++) {
        float p0s[4], p3s[4];
#pragma unroll
        for (int rt = 0; rt < 4; rt++) {
          p0s[rt] = __shfl(accP[rt][ct][0], lup, 64);
          p3s[rt] = __shfl(accP[rt][ct][3], ldn, 64);
        }
#pragma unroll
        for (int rt = 0; rt < 4; rt++)
#pragma unroll
          for (int reg = 0; reg < 4; reg++) {
            float pv = (reg > 0) ? accP[rt][ct][reg - 1] : ((q > 0) ? p3s[rt] : p3s[(rt + 3) & 3]);
            float nx = (reg < 3) ? accP[rt][ct][reg + 1] : ((q < 3) ? p0s[rt] : p0s[(rt + 1) & 3]);
            float o = a0r[rt][reg] * pv + a1r[rt][reg] * nx
                    + a2r[rt][reg] * accP[rt][ct][reg]
                    + h2r[rt][ct][reg] + b4[ct];
            sh_hb[(rt * 16 + q * 4 + reg) * KPAD + cb + ct * 16 + l] = (__bf16)o;
          }
      }
    }
    __syncthreads();
  }

  // ---------------- head MLP: silu(h@h1W+h1b), then h@h2W+h2b ----------------
  {
    f32x4 acc[4][4];
#pragma unroll
    for (int rt = 0; rt < 4; rt++)
#pragma unroll
      for (int ct = 0; ct < 4; ct++) acc[rt][ct] = (f32x4)0.0f;
    mfma_mm<8>(WP + OFF_H1W, acc, sh_hb, l, q, colbase8);
    __syncthreads();

    float b4[4];
#pragma unroll
    for (int ct = 0; ct < 4; ct++) b4[ct] = h1b[cb + ct * 16 + l];
#pragma unroll
    for (int rt = 0; rt < 4; rt++)
#pragma unroll
      for (int reg = 0; reg < 4; reg++) {
        int n = rt * 16 + q * 4 + reg;
#pragma unroll
        for (int ct = 0; ct < 4; ct++) {
          float o = acc[rt][ct][reg] + b4[ct];
          o = o / (1.0f + expf(-o));
          sh_hb[n * KPAD + cb + ct * 16 + l] = (__bf16)o;
        }
      }
    __syncthreads();

    { // final 256 -> 2, all 256 threads: split-K by 2 + pair combine
      int n = tid >> 2, c = (tid >> 1) & 1, half = tid & 1;
      const float* wrow = h2wt + c * 256 + half * 128;
      const __bf16* hrow = sh_hb + n * KPAD + half * 128;
      float o = half ? 0.0f : h2b[c];
#pragma unroll 4
      for (int k8 = 0; k8 < 16; k8++) {
        bf16x8 hv = *(const bf16x8*)(hrow + k8 * 8);
        f32x4 w0 = *(const f32x4*)(wrow + k8 * 8);
        f32x4 w1 = *(const f32x4*)(wrow + k8 * 8 + 4);
#pragma unroll
        for (int j = 0; j < 4; j++) o = fmaf((float)hv[j], w0[j], o);
#pragma unroll
        for (int j = 0; j < 4; j++) o = fmaf((float)hv[4 + j], w1[j], o);
      }
      o += __shfl_xor(o, 1, 64);
      if (!half) out[b * 128 + 2 * n + c] = o;
    }
  }
}

extern "C" void kernel_launch(void* const* d_in, const int* in_sizes, int n_in,
                              void* d_out, int out_size, void* d_ws, size_t ws_size,
                              hipStream_t stream)
{
  auto fp = [&](int i) { return (const float*)d_in[i]; };
  __bf16* wp   = (__bf16*)d_ws;
  float* h2wt  = (float*)(wp + OFF_END);        // 512 fp32
  float* dtemb = h2wt + 512;                    // 2048*128 fp32

  conv_pack<<<160, 256, 0, stream>>>(fp(4),  wp + OFF_W0,  134, 160);
  conv_pack<<<160, 256, 0, stream>>>(fp(20), wp + OFF_SK0, 134, 160);
  conv_pack<<<256, 256, 0, stream>>>(fp(8),  wp + OFF_W1,  256, 256);
  conv_pack<<<256, 256, 0, stream>>>(fp(21), wp + OFF_SK1, 256, 256);
  conv_pack<<<256, 256, 0, stream>>>(fp(12), wp + OFF_W2,  256, 256);
  conv_pack<<<256, 256, 0, stream>>>(fp(22), wp + OFF_SK2, 256, 256);
  conv_pack<<<256, 256, 0, stream>>>(fp(16), wp + OFF_W3,  256, 256);
  conv_pack<<<256, 256, 0, stream>>>(fp(23), wp + OFF_H1W, 256, 256);
  transpose_h2w<<<1, 512, 0, stream>>>(fp(25), h2wt);
  temb_kernel<<<2048, 128, 0, stream>>>((const int*)d_in[1], fp(2), fp(3), dtemb);

  gat_poly_kernel<<<2048, 256, 0, stream>>>(
      fp(0),
      fp(5),  fp(6),  fp(7),
      fp(9),  fp(10), fp(11),
      fp(13), fp(14), fp(15),
      fp(17), fp(18), fp(19),
      fp(24), fp(26),
      wp, h2wt, dtemb,
      (float*)d_out);
}

// Round 6
// 431.896 us; speedup vs baseline: 1.2350x; 1.2350x over previous
//
#include <hip/hip_runtime.h>
#include <hip/hip_bf16.h>

#define VN    64
#define KPAD  264   // sh_hb bf16 stride: rows 16B-aligned (528B)

typedef __bf16 bf16x8 __attribute__((ext_vector_type(8)));
typedef float  f32x4  __attribute__((ext_vector_type(4)));

// packed-weight bf16 element offsets in d_ws
#define OFF_W0   0
#define OFF_SK0  40960
#define OFF_W1   81920
#define OFF_SK1  147456
#define OFF_W2   212992
#define OFF_SK2  278528
#define OFF_W3   344064
#define OFF_H1W  409600
#define OFF_END  475136            // end of packed weights (bf16 elems)

// one kernel packs all 8 weight mats (fp32 -> bf16 fragment layout) + h2wt.
// blocks 0..159: W0, 160..319: sk0, then 6 x 256 blocks (W1,sk1,W2,sk2,W3,h1W),
// blocks 1856..1857: h2W transpose (512 fp32).
__global__ void pack_all(const float* __restrict__ W0s, const float* __restrict__ sk0s,
                         const float* __restrict__ W1s, const float* __restrict__ sk1s,
                         const float* __restrict__ W2s, const float* __restrict__ sk2s,
                         const float* __restrict__ W3s, const float* __restrict__ h1Ws,
                         const float* __restrict__ h2W, float* __restrict__ h2wt,
                         __bf16* __restrict__ wp)
{
  int blk = blockIdx.x;
  if (blk >= 1856) {
    int idx = (blk - 1856) * 256 + threadIdx.x;   // 0..511
    int c = idx >> 8, k = idx & 255;
    h2wt[idx] = h2W[k * 2 + c];
    return;
  }
  const float* src; int fin, dstoff, rel;
  if (blk < 320) {
    if (blk < 160) { src = W0s;  dstoff = OFF_W0;  rel = blk; }
    else           { src = sk0s; dstoff = OFF_SK0; rel = blk - 160; }
    fin = 134;
  } else {
    int r = (blk - 320) >> 8;                      // 0..5
    rel = (blk - 320) & 255;
    const float* srcs[6] = {W1s, sk1s, W2s, sk2s, W3s, h1Ws};
    const int    offs[6] = {OFF_W1, OFF_SK1, OFF_W2, OFF_SK2, OFF_W3, OFF_H1W};
    src = srcs[r]; dstoff = offs[r]; fin = 256;
  }
  int idx = rel * 256 + threadIdx.x;
  int rr = idx & 7, n = (idx >> 3) & 255, c = idx >> 11;
  int k = c * 8 + rr;
  float v = (k < fin) ? src[k * 256 + n] : 0.0f;
  wp[dstoff + idx] = (__bf16)v;
}

__global__ void temb_kernel(const int* __restrict__ t, const float* __restrict__ tW,
                            const float* __restrict__ tb, float* __restrict__ d_temb)
{
  __shared__ float se[128];
  int b = blockIdx.x, tid = threadIdx.x;
  int fi = tid & 63;
  float fr = expf(-logf(10000.0f) * (float)fi / 63.0f);
  float te = (float)t[b] * fr;
  se[tid] = (tid < 64) ? sinf(te) : cosf(te);
  __syncthreads();
  float a = tb[tid];
  for (int k = 0; k < 128; k++)
    a = fmaf(se[k], tW[k * 128 + tid], a);
  d_temb[b * 128 + tid] = a / (1.0f + expf(-a));
}

// single-B matmul: acc += A(64 x 32*KS from LDS) @ B(packed global)
template<int KS>
__device__ __forceinline__ void mfma_mm(const __bf16* __restrict__ Bp,
                                        f32x4 acc[4][4],
                                        const __bf16* __restrict__ shA,
                                        int l, int q, int colbase8)
{
#pragma unroll
  for (int s = 0; s < KS; s++) {
    bf16x8 af[4], bfr[4];
#pragma unroll
    for (int rt = 0; rt < 4; rt++)
      af[rt] = *(const bf16x8*)(shA + (rt * 16 + l) * KPAD + s * 32 + q * 8);
#pragma unroll
    for (int ct = 0; ct < 4; ct++)
      bfr[ct] = *(const bf16x8*)(Bp + (s * 4 + q) * 2048 + colbase8 + ct * 128);
#pragma unroll
    for (int rt = 0; rt < 4; rt++)
#pragma unroll
      for (int ct = 0; ct < 4; ct++)
        acc[rt][ct] = __builtin_amdgcn_mfma_f32_16x16x32_bf16(af[rt], bfr[ct], acc[rt][ct], 0, 0, 0);
  }
}

// dual-B matmul: shared A fragments, accW += A@Bw, accK += A@Bk
template<int KS>
__device__ __forceinline__ void mfma_dual(const __bf16* __restrict__ Bw,
                                          const __bf16* __restrict__ Bk,
                                          f32x4 accW[4][4], f32x4 accK[4][4],
                                          const __bf16* __restrict__ shA,
                                          int l, int q, int colbase8)
{
#pragma unroll
  for (int s = 0; s < KS; s++) {
    bf16x8 af[4], bw[4], bk[4];
#pragma unroll
    for (int rt = 0; rt < 4; rt++)
      af[rt] = *(const bf16x8*)(shA + (rt * 16 + l) * KPAD + s * 32 + q * 8);
#pragma unroll
    for (int ct = 0; ct < 4; ct++) {
      bw[ct] = *(const bf16x8*)(Bw + (s * 4 + q) * 2048 + colbase8 + ct * 128);
      bk[ct] = *(const bf16x8*)(Bk + (s * 4 + q) * 2048 + colbase8 + ct * 128);
    }
#pragma unroll
    for (int rt = 0; rt < 4; rt++)
#pragma unroll
      for (int ct = 0; ct < 4; ct++) {
        accW[rt][ct] = __builtin_amdgcn_mfma_f32_16x16x32_bf16(af[rt], bw[ct], accW[rt][ct], 0, 0, 0);
        accK[rt][ct] = __builtin_amdgcn_mfma_f32_16x16x32_bf16(af[rt], bk[ct], accK[rt][ct], 0, 0, 0);
      }
  }
}

__global__ __launch_bounds__(256, 2)
void gat_poly_kernel(const float* __restrict__ x,
                     const float* __restrict__ as0, const float* __restrict__ at0, const float* __restrict__ b0,
                     const float* __restrict__ as1, const float* __restrict__ at1, const float* __restrict__ b1,
                     const float* __restrict__ as2, const float* __restrict__ at2, const float* __restrict__ b2,
                     const float* __restrict__ as3, const float* __restrict__ at3, const float* __restrict__ b3,
                     const float* __restrict__ h1b, const float* __restrict__ h2b,
                     const __bf16* __restrict__ WP,
                     const float* __restrict__ h2wt,
                     const float* __restrict__ d_temb,
                     float* __restrict__ out)
{
  __shared__ __bf16 sh_hb[VN * KPAD];   // activations bf16 (MFMA A source)
  __shared__ float  sh_temb[128];
  __shared__ float  sh_ssp[VN * 4];     // layer-3 per-wave score partials
  __shared__ float  sh_stp[VN * 4];
  __shared__ float  sh_al[VN][3];       // layer-3 alphas

  const int b    = blockIdx.x;
  const int tid  = threadIdx.x;
  const int w    = tid >> 6;
  const int lane = tid & 63;
  const int l    = lane & 15;
  const int q    = lane >> 4;
  const int cb   = w * 64;
  const int colbase8 = (cb + l) * 8;
  const int lup  = (lane + 16) & 63;    // q+1 group (wraps)
  const int ldn  = (lane + 48) & 63;    // q-1 group (wraps)

  if (tid < 128) sh_temb[tid] = d_temb[b * 128 + tid];
  __syncthreads();

  // ------------- h0 = [coords(2), pos(4), temb(128)], zero pad to 160 --------
  for (int idx = tid; idx < VN * 160; idx += 256) {
    int n = idx / 160, k = idx - n * 160;
    float v = 0.0f;
    if (k < 2) {
      v = x[b * 128 + 2 * n + k];
    } else if (k < 6) {
      float ph  = (float)n * 0.09817477042468103f;  // 2*pi/64
      float arg = (k < 4) ? ph : 2.0f * ph;
      v = ((k & 1) == 0) ? sinf(arg) : cosf(arg);
    } else if (k < 134) {
      v = sh_temb[k - 6];
    }
    sh_hb[n * KPAD + k] = (__bf16)v;
  }
  __syncthreads();

  const int WOFFS[3]  = {OFF_W0, OFF_W1, OFF_W2};
  const int SOFFS[3]  = {OFF_SK0, OFF_SK1, OFF_SK2};
  const float* Asr[3] = {as0, as1, as2};
  const float* Atg[3] = {at0, at1, at2};
  const float* Bs[3]  = {b0, b1, b2};

  // ---------------- GAT layers 0..2 (NH=4, FOUT=64, concat + elu) ------------
  for (int li = 0; li < 3; li++) {
    f32x4 accP[4][4], accS[4][4];
#pragma unroll
    for (int rt = 0; rt < 4; rt++)
#pragma unroll
      for (int ct = 0; ct < 4; ct++) { accP[rt][ct] = (f32x4)0.0f; accS[rt][ct] = (f32x4)0.0f; }

    if (li == 0) mfma_dual<5>(WP + OFF_W0,   WP + OFF_SK0,   accP, accS, sh_hb, l, q, colbase8);
    else         mfma_dual<8>(WP + WOFFS[li], WP + SOFFS[li], accP, accS, sh_hb, l, q, colbase8);

    // -------- scores: wave w == head w; fully in-register ----------
    float ca[4], ta[4];
#pragma unroll
    for (int ct = 0; ct < 4; ct++) {
      ca[ct] = Asr[li][cb + ct * 16 + l];
      ta[ct] = Atg[li][cb + ct * 16 + l];
    }
    float ssA[4][4], stA[4][4];
#pragma unroll
    for (int rt = 0; rt < 4; rt++)
#pragma unroll
      for (int reg = 0; reg < 4; reg++) {
        float ss = accP[rt][0][reg] * ca[0] + accP[rt][1][reg] * ca[1]
                 + accP[rt][2][reg] * ca[2] + accP[rt][3][reg] * ca[3];
        float st = accP[rt][0][reg] * ta[0] + accP[rt][1][reg] * ta[1]
                 + accP[rt][2][reg] * ta[2] + accP[rt][3][reg] * ta[3];
#pragma unroll
        for (int m = 8; m >= 1; m >>= 1) {
          ss += __shfl_xor(ss, m, 64);
          st += __shfl_xor(st, m, 64);
        }
        ssA[rt][reg] = ss;
        stA[rt][reg] = st;
      }

    // -------- softmax over {prv,nxt,self} edges, in-register --------
    float al0[4][4], al1[4][4], al2[4][4];
    {
      float s0s[4], s3s[4];
#pragma unroll
      for (int rt = 0; rt < 4; rt++) {
        s0s[rt] = __shfl(ssA[rt][0], lup, 64);
        s3s[rt] = __shfl(ssA[rt][3], ldn, 64);
      }
#pragma unroll
      for (int rt = 0; rt < 4; rt++)
#pragma unroll
        for (int reg = 0; reg < 4; reg++) {
          float ssp = (reg > 0) ? ssA[rt][reg - 1] : ((q > 0) ? s3s[rt] : s3s[(rt + 3) & 3]);
          float ssx = (reg < 3) ? ssA[rt][reg + 1] : ((q < 3) ? s0s[rt] : s0s[(rt + 1) & 3]);
          float stg = stA[rt][reg];
          float e0 = ssp + stg;          e0 = (e0 < 0.0f) ? 0.2f * e0 : e0;
          float e1 = ssx + stg;          e1 = (e1 < 0.0f) ? 0.2f * e1 : e1;
          float e2 = ssA[rt][reg] + stg; e2 = (e2 < 0.0f) ? 0.2f * e2 : e2;
          float mx = fmaxf(e0, fmaxf(e1, e2));
          float x0 = expf(e0 - mx), x1 = expf(e1 - mx), x2 = expf(e2 - mx);
          float inv = 1.0f / (x0 + x1 + x2 + 1e-16f);
          al0[rt][reg] = x0 * inv;
          al1[rt][reg] = x1 * inv;
          al2[rt][reg] = x2 * inv;
        }
    }

    __syncthreads();   // all waves done reading sh_hb

    // -------- epilogue: skip + alpha-weighted neighbor gather (shuffles) -----
    {
      float b4[4];
#pragma unroll
      for (int ct = 0; ct < 4; ct++) b4[ct] = Bs[li][cb + ct * 16 + l];
#pragma unroll
      for (int ct = 0; ct < 4; ct++) {
        float p0s[4], p3s[4];
#pragma unroll
        for (int rt = 0; rt < 4; rt++) {
          p0s[rt] = __shfl(accP[rt][ct][0], lup, 64);
          p3s[rt] = __shfl(accP[rt][ct][3], ldn, 64);
        }
#pragma unroll
        for (int rt = 0; rt < 4; rt++)
#pragma unroll
          for (int reg = 0; reg < 4; reg++) {
            float pv = (reg > 0) ? accP[rt][ct][reg - 1] : ((q > 0) ? p3s[rt] : p3s[(rt + 3) & 3]);
            float nx = (reg < 3) ? accP[rt][ct][reg + 1] : ((q < 3) ? p0s[rt] : p0s[(rt + 1) & 3]);
            float o = accS[rt][ct][reg]
                    + al0[rt][reg] * pv + al1[rt][reg] * nx
                    + al2[rt][reg] * accP[rt][ct][reg] + b4[ct];
            o = (o > 0.0f) ? o : (expf(o) - 1.0f);   // elu
            sh_hb[(rt * 16 + q * 4 + reg) * KPAD + cb + ct * 16 + l] = (__bf16)o;
          }
      }
    }
    __syncthreads();
  }

  // ---------------- GAT layer 3 (NH=1, FOUT=256, identity skip, no act) ------
  {
    f32x4 accP[4][4];
#pragma unroll
    for (int rt = 0; rt < 4; rt++)
#pragma unroll
      for (int ct = 0; ct < 4; ct++) accP[rt][ct] = (f32x4)0.0f;
    mfma_mm<8>(WP + OFF_W3, accP, sh_hb, l, q, colbase8);

    { // per-wave partial scores over this wave's 64 cols
      float ca[4], ta[4];
#pragma unroll
      for (int ct = 0; ct < 4; ct++) {
        ca[ct] = as3[cb + ct * 16 + l];
        ta[ct] = at3[cb + ct * 16 + l];
      }
#pragma unroll
      for (int rt = 0; rt < 4; rt++)
#pragma unroll
        for (int reg = 0; reg < 4; reg++) {
          float ss = accP[rt][0][reg] * ca[0] + accP[rt][1][reg] * ca[1]
                   + accP[rt][2][reg] * ca[2] + accP[rt][3][reg] * ca[3];
          float st = accP[rt][0][reg] * ta[0] + accP[rt][1][reg] * ta[1]
                   + accP[rt][2][reg] * ta[2] + accP[rt][3][reg] * ta[3];
#pragma unroll
          for (int m = 8; m >= 1; m >>= 1) {
            ss += __shfl_xor(ss, m, 64);
            st += __shfl_xor(st, m, 64);
          }
          if (l == 0) {
            int n = rt * 16 + q * 4 + reg;
            sh_ssp[n * 4 + w] = ss;
            sh_stp[n * 4 + w] = st;
          }
        }
    }
    __syncthreads();   // partials visible

    if (tid < 64) {    // single wave: combine partials + softmax
      int n = tid;
      float ssn = sh_ssp[n * 4] + sh_ssp[n * 4 + 1] + sh_ssp[n * 4 + 2] + sh_ssp[n * 4 + 3];
      float stn = sh_stp[n * 4] + sh_stp[n * 4 + 1] + sh_stp[n * 4 + 2] + sh_stp[n * 4 + 3];
      float ssp = __shfl(ssn, (n + 63) & 63, 64);
      float ssx = __shfl(ssn, (n + 1) & 63, 64);
      float e0 = ssp + stn; e0 = (e0 < 0.0f) ? 0.2f * e0 : e0;
      float e1 = ssx + stn; e1 = (e1 < 0.0f) ? 0.2f * e1 : e1;
      float e2 = ssn + stn; e2 = (e2 < 0.0f) ? 0.2f * e2 : e2;
      float mx = fmaxf(e0, fmaxf(e1, e2));
      float x0 = expf(e0 - mx), x1 = expf(e1 - mx), x2 = expf(e2 - mx);
      float inv = 1.0f / (x0 + x1 + x2 + 1e-16f);
      sh_al[n][0] = x0 * inv;
      sh_al[n][1] = x1 * inv;
      sh_al[n][2] = x2 * inv;
    }
    __syncthreads();

    { // epilogue: alpha gather (shuffles) + residual (read from sh_hb) + b3
      float b4[4];
#pragma unroll
      for (int ct = 0; ct < 4; ct++) b4[ct] = b3[cb + ct * 16 + l];
      float a0r[4][4], a1r[4][4], a2r[4][4];
#pragma unroll
      for (int rt = 0; rt < 4; rt++)
#pragma unroll
        for (int reg = 0; reg < 4; reg++) {
          int n = rt * 16 + q * 4 + reg;
          a0r[rt][reg] = sh_al[n][0];
          a1r[rt][reg] = sh_al[n][1];
          a2r[rt][reg] = sh_al[n][2];
        }
#pragma unroll
      for (int ct = 0; ct < 4; ct++) {
        float p0s[4], p3s[4];
#pragma unroll
        for (int rt = 0; rt < 4; rt++) {
          p0s[rt] = __shfl(accP[rt][ct][0], lup, 64);
          p3s[rt] = __shfl(accP[rt][ct][3], ldn, 64);
        }
#pragma unroll
        for (int rt = 0; rt < 4; rt++)
#pragma unroll
          for (int reg = 0; reg < 4; reg++) {
            float pv = (reg > 0) ? accP[rt][ct][reg - 1] : ((q > 0) ? p3s[rt] : p3s[(rt + 3) & 3]);
            float nx = (reg < 3) ? accP[rt][ct][reg + 1] : ((q < 3) ? p0s[rt] : p0s[(rt + 1) & 3]);
            int addr = (rt * 16 + q * 4 + reg) * KPAD + cb + ct * 16 + l;
            float hres = (float)sh_hb[addr];           // layer-2 out (bf16), lane-owned
            float o = a0r[rt][reg] * pv + a1r[rt][reg] * nx
                    + a2r[rt][reg] * accP[rt][ct][reg]
                    + hres + b4[ct];
            sh_hb[addr] = (__bf16)o;
          }
      }
    }
    __syncthreads();
  }

  // ---------------- head MLP: silu(h@h1W+h1b), then h@h2W+h2b ----------------
  {
    f32x4 acc[4][4];
#pragma unroll
    for (int rt = 0; rt < 4; rt++)
#pragma unroll
      for (int ct = 0; ct < 4; ct++) acc[rt][ct] = (f32x4)0.0f;
    mfma_mm<8>(WP + OFF_H1W, acc, sh_hb, l, q, colbase8);
    __syncthreads();

    float b4[4];
#pragma unroll
    for (int ct = 0; ct < 4; ct++) b4[ct] = h1b[cb + ct * 16 + l];
#pragma unroll
    for (int rt = 0; rt < 4; rt++)
#pragma unroll
      for (int reg = 0; reg < 4; reg++) {
        int n = rt * 16 + q * 4 + reg;
#pragma unroll
        for (int ct = 0; ct < 4; ct++) {
          float o = acc[rt][ct][reg] + b4[ct];
          o = o / (1.0f + expf(-o));
          sh_hb[n * KPAD + cb + ct * 16 + l] = (__bf16)o;
        }
      }
    __syncthreads();

    { // final 256 -> 2, all 256 threads: split-K by 2 + pair combine
      int n = tid >> 2, c = (tid >> 1) & 1, half = tid & 1;
      const float* wrow = h2wt + c * 256 + half * 128;
      const __bf16* hrow = sh_hb + n * KPAD + half * 128;
      float o = half ? 0.0f : h2b[c];
#pragma unroll 4
      for (int k8 = 0; k8 < 16; k8++) {
        bf16x8 hv = *(const bf16x8*)(hrow + k8 * 8);
        f32x4 w0 = *(const f32x4*)(wrow + k8 * 8);
        f32x4 w1 = *(const f32x4*)(wrow + k8 * 8 + 4);
#pragma unroll
        for (int j = 0; j < 4; j++) o = fmaf((float)hv[j], w0[j], o);
#pragma unroll
        for (int j = 0; j < 4; j++) o = fmaf((float)hv[4 + j], w1[j], o);
      }
      o += __shfl_xor(o, 1, 64);
      if (!half) out[b * 128 + 2 * n + c] = o;
    }
  }
}

extern "C" void kernel_launch(void* const* d_in, const int* in_sizes, int n_in,
                              void* d_out, int out_size, void* d_ws, size_t ws_size,
                              hipStream_t stream)
{
  auto fp = [&](int i) { return (const float*)d_in[i]; };
  __bf16* wp   = (__bf16*)d_ws;
  float* h2wt  = (float*)(wp + OFF_END);        // 512 fp32
  float* dtemb = h2wt + 512;                    // 2048*128 fp32

  pack_all<<<1858, 256, 0, stream>>>(fp(4), fp(20), fp(8), fp(21),
                                     fp(12), fp(22), fp(16), fp(23),
                                     fp(25), h2wt, wp);
  temb_kernel<<<2048, 128, 0, stream>>>((const int*)d_in[1], fp(2), fp(3), dtemb);

  gat_poly_kernel<<<2048, 256, 0, stream>>>(
      fp(0),
      fp(5),  fp(6),  fp(7),
      fp(9),  fp(10), fp(11),
      fp(13), fp(14), fp(15),
      fp(17), fp(18), fp(19),
      fp(24), fp(26),
      wp, h2wt, dtemb,
      (float*)d_out);
}